// Round 2
// baseline (1744.006 us; speedup 1.0000x reference)
//
#include <hip/hip_runtime.h>
#include <hip/hip_fp16.h>

#define DEVI __device__ __forceinline__

typedef __attribute__((ext_vector_type(4))) float f32x4;
typedef __attribute__((ext_vector_type(8))) short bf16x8;
typedef __attribute__((ext_vector_type(8))) _Float16 f16x8;
typedef __attribute__((ext_vector_type(2))) _Float16 f16x2;
typedef unsigned long long ull;

DEVI ushort f2bf(float x) {
  union { float f; unsigned u; } v; v.f = x;
  unsigned r = v.u + 0x7fffu + ((v.u >> 16) & 1u);
  return (ushort)(r >> 16);
}
DEVI float bf2f(ushort b) {
  union { unsigned u; float f; } v; v.u = ((unsigned)b) << 16; return v.f;
}
DEVI unsigned packh2(float a, float b) {
  return ((unsigned)__half_as_ushort(__float2half(b)) << 16) |
         (unsigned)__half_as_ushort(__float2half(a));
}
DEVI float dot2(unsigned a, unsigned b, float c) {
#if __has_builtin(__builtin_amdgcn_fdot2)
  return __builtin_amdgcn_fdot2(__builtin_bit_cast(f16x2, a),
                                __builtin_bit_cast(f16x2, b), c, false);
#else
  f16x2 ha = __builtin_bit_cast(f16x2, a), hb = __builtin_bit_cast(f16x2, b);
  return c + (float)ha[0] * (float)hb[0] + (float)ha[1] * (float)hb[1];
#endif
}
DEVI float sigmoidf_(float x) { return 1.f / (1.f + __expf(-x)); }
// NaN-free fast tanh: e=exp(2x); 1-2/(e+1). e=inf -> 1, e=0 -> -1.
DEVI float tanh_fast(float x) {
  float e = __expf(2.f * x);
  return 1.f - 2.f / (e + 1.f);
}

// relaxed agent-scope (L3 coherence point) 64-bit tagged-word accesses
DEVI void gstore64(ull* p, ull v) {
  __hip_atomic_store(p, v, __ATOMIC_RELAXED, __HIP_MEMORY_SCOPE_AGENT);
}
DEVI ull gload64(const ull* p) {
  return __hip_atomic_load(p, __ATOMIC_RELAXED, __HIP_MEMORY_SCOPE_AGENT);
}

// ---------------------------------------------------------------------------
// Generic 128x128-tile bf16 MFMA GEMM:  C[M,N] = A[M,K] @ Bw[N,K]^T + bias
// SPLIT=true: hi/lo split-bf16, 3 MFMA passes (~fp32 accuracy).
// ABF16/BBF16: operand already bf16 (ushort) in gmem.
// ---------------------------------------------------------------------------
template<bool SPLIT, bool ABF16, bool BBF16>
__global__ __launch_bounds__(256)
void gemm_kernel(const void* __restrict__ A_, int lda, const int* __restrict__ Aidx,
                 const void* __restrict__ Bw_, int ldb,
                 const float* __restrict__ bias, float* __restrict__ C,
                 int N, int K)
{
  constexpr int BK  = SPLIT ? 32 : 64;
  constexpr int LDT = BK + 8;
  constexpr int NV  = (128 * BK / 4) / 256;

  __shared__ ushort Ah[128 * LDT];
  __shared__ ushort Bh[128 * LDT];
  __shared__ ushort Al[SPLIT ? 128 * LDT : 4];
  __shared__ ushort Bl[SPLIT ? 128 * LDT : 4];

  const int tid  = threadIdx.x;
  const int bm   = blockIdx.x * 128, bn = blockIdx.y * 128;
  const int lane = tid & 63, wave = tid >> 6;
  const int wr   = wave >> 1, wc = wave & 1;
  const int fr   = lane & 15, quad = lane >> 4;

  f32x4 acc[4][4] = {};

  for (int kt = 0; kt < K; kt += BK) {
    __syncthreads();
#pragma unroll
    for (int i = 0; i < NV; ++i) {
      int v   = i * 256 + tid;
      int row = v / (BK / 4);
      int c4  = (v % (BK / 4)) * 4;
      int arow = Aidx ? Aidx[bm + row] : (bm + row);
      if (ABF16) {
        const ushort* A = (const ushort*)A_;
        ushort4 h = *reinterpret_cast<const ushort4*>(A + (size_t)arow * lda + kt + c4);
        *reinterpret_cast<ushort4*>(&Ah[row * LDT + c4]) = h;
      } else {
        const float* A = (const float*)A_;
        const float4 x = *reinterpret_cast<const float4*>(A + (size_t)arow * lda + kt + c4);
        ushort4 h; h.x = f2bf(x.x); h.y = f2bf(x.y); h.z = f2bf(x.z); h.w = f2bf(x.w);
        *reinterpret_cast<ushort4*>(&Ah[row * LDT + c4]) = h;
        if (SPLIT) {
          ushort4 l;
          l.x = f2bf(x.x - bf2f(h.x)); l.y = f2bf(x.y - bf2f(h.y));
          l.z = f2bf(x.z - bf2f(h.z)); l.w = f2bf(x.w - bf2f(h.w));
          *reinterpret_cast<ushort4*>(&Al[row * LDT + c4]) = l;
        }
      }
    }
#pragma unroll
    for (int i = 0; i < NV; ++i) {
      int v   = i * 256 + tid;
      int row = v / (BK / 4);
      int c4  = (v % (BK / 4)) * 4;
      if (BBF16) {
        const ushort* B16 = (const ushort*)Bw_;
        ushort4 h = *reinterpret_cast<const ushort4*>(B16 + (size_t)(bn + row) * ldb + kt + c4);
        *reinterpret_cast<ushort4*>(&Bh[row * LDT + c4]) = h;
      } else {
        const float* Bw = (const float*)Bw_;
        const float4 x = *reinterpret_cast<const float4*>(Bw + (size_t)(bn + row) * ldb + kt + c4);
        ushort4 h; h.x = f2bf(x.x); h.y = f2bf(x.y); h.z = f2bf(x.z); h.w = f2bf(x.w);
        *reinterpret_cast<ushort4*>(&Bh[row * LDT + c4]) = h;
        if (SPLIT) {
          ushort4 l;
          l.x = f2bf(x.x - bf2f(h.x)); l.y = f2bf(x.y - bf2f(h.y));
          l.z = f2bf(x.z - bf2f(h.z)); l.w = f2bf(x.w - bf2f(h.w));
          *reinterpret_cast<ushort4*>(&Bl[row * LDT + c4]) = l;
        }
      }
    }
    __syncthreads();
#pragma unroll
    for (int ks = 0; ks < BK; ks += 32) {
      bf16x8 ah[4], bh[4];
#pragma unroll
      for (int i = 0; i < 4; ++i) {
        ah[i] = *reinterpret_cast<const bf16x8*>(&Ah[(wr * 64 + i * 16 + fr) * LDT + ks + quad * 8]);
        bh[i] = *reinterpret_cast<const bf16x8*>(&Bh[(wc * 64 + i * 16 + fr) * LDT + ks + quad * 8]);
      }
      if (SPLIT) {
        bf16x8 al[4], bl[4];
#pragma unroll
        for (int i = 0; i < 4; ++i) {
          al[i] = *reinterpret_cast<const bf16x8*>(&Al[(wr * 64 + i * 16 + fr) * LDT + ks + quad * 8]);
          bl[i] = *reinterpret_cast<const bf16x8*>(&Bl[(wc * 64 + i * 16 + fr) * LDT + ks + quad * 8]);
        }
#pragma unroll
        for (int i = 0; i < 4; ++i)
#pragma unroll
          for (int j = 0; j < 4; ++j) {
            acc[i][j] = __builtin_amdgcn_mfma_f32_16x16x32_bf16(ah[i], bh[j], acc[i][j], 0, 0, 0);
            acc[i][j] = __builtin_amdgcn_mfma_f32_16x16x32_bf16(ah[i], bl[j], acc[i][j], 0, 0, 0);
            acc[i][j] = __builtin_amdgcn_mfma_f32_16x16x32_bf16(al[i], bh[j], acc[i][j], 0, 0, 0);
          }
      } else {
#pragma unroll
        for (int i = 0; i < 4; ++i)
#pragma unroll
          for (int j = 0; j < 4; ++j)
            acc[i][j] = __builtin_amdgcn_mfma_f32_16x16x32_bf16(ah[i], bh[j], acc[i][j], 0, 0, 0);
      }
    }
  }
#pragma unroll
  for (int i = 0; i < 4; ++i)
#pragma unroll
    for (int j = 0; j < 4; ++j)
#pragma unroll
      for (int r = 0; r < 4; ++r) {
        int m = bm + wr * 64 + i * 16 + quad * 4 + r;
        int n = bn + wc * 64 + j * 16 + fr;
        float vv = acc[i][j][r];
        if (bias) vv += bias[n];
        C[(size_t)m * N + n] = vv;
      }
}

// ---------------------------------------------------------------------------
__global__ void prep_kernel(const float* __restrict__ Wq, float* __restrict__ WqT,
                            const float* __restrict__ b_ih, const float* __restrict__ b_hh,
                            float* __restrict__ bsum)
{
  int idx = blockIdx.x * 256 + threadIdx.x;
  if (idx < 65536) {
    int e = idx >> 8, d = idx & 255;
    WqT[idx] = Wq[d * 256 + e];
  } else if (idx < 66560) {
    int n = idx - 65536;
    bsum[n] = b_ih[n] + b_hh[n];
  }
}

// sb[r] = keys[r,:] . bq
__global__ void sb_kernel(const float* __restrict__ keys, const float* __restrict__ bq,
                          float* __restrict__ sb)
{
  int row  = blockIdx.x * 4 + (threadIdx.x >> 6);
  int lane = threadIdx.x & 63;
  const float* kr = keys + (size_t)row * 256;
  float acc = kr[lane] * bq[lane] + kr[64 + lane] * bq[64 + lane]
            + kr[128 + lane] * bq[128 + lane] + kr[192 + lane] * bq[192 + lane];
#pragma unroll
  for (int off = 1; off < 64; off <<= 1) acc += __shfl_xor(acc, off);
  if (lane == 0) sb[row] = acc;
}

// f32 -> bf16 convert
__global__ void cvt_kernel(const float* __restrict__ src, ushort* __restrict__ dst, int n4)
{
  int i = blockIdx.x * 256 + threadIdx.x;
  if (i < n4) {
    float4 x = reinterpret_cast<const float4*>(src)[i];
    ushort4 h; h.x = f2bf(x.x); h.y = f2bf(x.y); h.z = f2bf(x.z); h.w = f2bf(x.w);
    reinterpret_cast<ushort4*>(dst)[i] = h;
  }
}

// ---------------------------------------------------------------------------
// Sequential scan, batch-decoupled: 16 independent groups of 8 blocks.
// Tagged 64-bit payloads (hi32 = t+1), parity double-buffered. 6 barriers and
// 2 cross-block L3 round-trips per step (structural minimum); Wh@h half of the
// gate matvec and all poll loads are issued under the first RT window.
// ---------------------------------------------------------------------------
struct ScanSmem2 {
  unsigned k2p[64][132];   // K2 slice, f16 pairs (stride 132: uint4-aligned, 2-way banks)
  unsigned vtp[256][35];   // V slice transposed [e][jp]
  unsigned xw[288];        // x = [ctx|h] f16 pairs, 4 chunks x 72
  unsigned psp[32];        // softmax p, f16 pairs
  float Erow[128];
  float gout[128];
  float cpart[4][128][2];  // ctx combine partials
  float scores[64];
  float sbs[64];
};

DEVI int xwi(int w) { return (w >> 6) * 72 + (w & 63); }

__global__ __launch_bounds__(512, 1)
void scan2_kernel(const float* __restrict__ E, const float* __restrict__ K2g,
                  const float* __restrict__ sbg, const float* __restrict__ valg,
                  const float* __restrict__ W_ih, const float* __restrict__ W_hh,
                  ushort* __restrict__ hcb16,
                  ull* __restrict__ Hx,    // [2][16][128]
                  ull* __restrict__ Px)    // [2][16][8][130]
{
  extern __shared__ char smraw[];
  ScanSmem2& sm = *reinterpret_cast<ScanSmem2*>(smraw);
  const int g = blockIdx.x, tid = threadIdx.x;
  const int b = g >> 3, ss = g & 7;

  // ---- persistent LDS init
  for (int idx = tid; idx < 64 * 128; idx += 512) {
    int j = idx >> 7, i = idx & 127;
    const float* src = K2g + (size_t)(b * 512 + ss * 64 + j) * 256 + 2 * i;
    sm.k2p[j][i] = packh2(src[0], src[1]);
  }
  for (int idx = tid; idx < 256 * 32; idx += 512) {
    int e = idx >> 5, jp = idx & 31;
    float v0 = valg[(size_t)(b * 512 + ss * 64 + 2 * jp) * 256 + e];
    float v1 = valg[(size_t)(b * 512 + ss * 64 + 2 * jp + 1) * 256 + e];
    sm.vtp[e][jp] = packh2(v0, v1);
  }
  if (tid < 64) sm.sbs[tid] = sbg[b * 512 + ss * 64 + tid];
  for (int i = tid; i < 288; i += 512) sm.xw[i] = 0;   // ctx0 = h0 = 0

  // ---- gate-weight slice -> registers (f16 pairs), 4 threads per gate row
  const int r  = tid >> 2, h4 = tid & 3;
  const int grow = (r >> 5) * 256 + ss * 32 + (r & 31);  // PyTorch i,f,g,o order
  const float* wsrc = (h4 < 2)
      ? (W_ih + (size_t)grow * 512 + 256 + h4 * 128)     // x[0:256] = ctx
      : (W_hh + (size_t)grow * 256 + (h4 - 2) * 128);    // x[256:512] = h
  unsigned wreg[64];
#pragma unroll
  for (int i = 0; i < 32; ++i) {
    float4 w4 = reinterpret_cast<const float4*>(wsrc)[i];
    wreg[2 * i]     = packh2(w4.x, w4.y);
    wreg[2 * i + 1] = packh2(w4.z, w4.w);
  }

  float c_reg = 0.f;          // cell state, tid<32 only
  __syncthreads();

  const size_t hxb = (size_t)b * 128;
  const size_t pxb = (size_t)b * (8 * 130);

  for (int t = 0; t <= 128; ++t) {
    // E prefetch for this step
    float epf = 0.f;
    if (t < 128 && tid < 128)
      epf = E[(size_t)(b * 128 + t) * 1024 + (tid >> 5) * 256 + ss * 32 + (tid & 31)];

    float accg = 0.f;
    if (t > 0) {
      const unsigned tag = (unsigned)t;
      const ull* PxP = Px + (size_t)((t - 1) & 1) * (16 * 8 * 130) + pxb;
      const int e2 = tid & 127, q = tid >> 7;
      const ull* p1 = &PxP[(2 * q) * 130 + e2];
      const ull* p2 = &PxP[(2 * q + 1) * 130 + e2];
      // issue ALL poll loads first (16 m/l words + 2 ctx-partial words)
      ull wml[16];
#pragma unroll
      for (int s3 = 0; s3 < 16; ++s3)
        wml[s3] = gload64(&PxP[(s3 >> 1) * 130 + 128 + (s3 & 1)]);
      ull w1 = gload64(p1), w2 = gload64(p2);

      // ---- phase 0 under the RT: Wh @ h(t-1) half of the gate matvec
      if (h4 >= 2) {
        const unsigned* xsrc = sm.xw + h4 * 72;
#pragma unroll
        for (int i = 0; i < 16; ++i) {
          uint4 xv = *reinterpret_cast<const uint4*>(xsrc + 4 * i);
          accg = dot2(wreg[4 * i + 0], xv.x, accg);
          accg = dot2(wreg[4 * i + 1], xv.y, accg);
          accg = dot2(wreg[4 * i + 2], xv.z, accg);
          accg = dot2(wreg[4 * i + 3], xv.w, accg);
        }
      }

      // ---- grouped spin: re-poll all stale words in one pipelined sweep
      for (;;) {
        unsigned pend = 0;
        ull nw[16];
#pragma unroll
        for (int s3 = 0; s3 < 16; ++s3)
          if ((unsigned)(wml[s3] >> 32) != tag)
            nw[s3] = gload64(&PxP[(s3 >> 1) * 130 + 128 + (s3 & 1)]);
#pragma unroll
        for (int s3 = 0; s3 < 16; ++s3)
          if ((unsigned)(wml[s3] >> 32) != tag) {
            wml[s3] = nw[s3];
            if ((unsigned)(nw[s3] >> 32) != tag) pend = 1;
          }
        if (!pend) break;
        __builtin_amdgcn_s_sleep(1);
      }
      while ((unsigned)(w1 >> 32) != tag) { __builtin_amdgcn_s_sleep(1); w1 = gload64(p1); }
      while ((unsigned)(w2 >> 32) != tag) { __builtin_amdgcn_s_sleep(1); w2 = gload64(p2); }

      float mv[8], lv[8];
#pragma unroll
      for (int s3 = 0; s3 < 8; ++s3) {
        mv[s3] = __uint_as_float((unsigned)wml[2 * s3]);
        lv[s3] = __uint_as_float((unsigned)wml[2 * s3 + 1]);
      }
      float M = mv[0];
#pragma unroll
      for (int s3 = 1; s3 < 8; ++s3) M = fmaxf(M, mv[s3]);
      float L = 0.f;
#pragma unroll
      for (int s3 = 0; s3 < 8; ++s3) L += lv[s3] * __expf(mv[s3] - M);
      float rcpL = 1.f / L;
      float wf0 = __expf(mv[2 * q] - M);
      float wf1 = __expf(mv[2 * q + 1] - M);
      f16x2 x1 = __builtin_bit_cast(f16x2, (unsigned)w1);
      f16x2 x2 = __builtin_bit_cast(f16x2, (unsigned)w2);
      sm.cpart[q][e2][0] = wf0 * (float)x1[0] + wf1 * (float)x2[0];
      sm.cpart[q][e2][1] = wf0 * (float)x1[1] + wf1 * (float)x2[1];
      __syncthreads();     // B1: cpart ready
      if (tid < 128) {
        float c0 = (sm.cpart[0][tid][0] + sm.cpart[1][tid][0]
                  + sm.cpart[2][tid][0] + sm.cpart[3][tid][0]) * rcpL;
        float c1 = (sm.cpart[0][tid][1] + sm.cpart[1][tid][1]
                  + sm.cpart[2][tid][1] + sm.cpart[3][tid][1]) * rcpL;
        sm.xw[xwi(tid)] = packh2(c0, c1);
        ushort* dst = hcb16 + (size_t)(b * 128 + (t - 1)) * 512 + 256 + 2 * tid;
        dst[0] = f2bf(c0); dst[1] = f2bf(c1);
      }
    }
    if (t == 128) break;
    if (tid < 128) sm.Erow[tid] = epf;
    __syncthreads();       // B2: xw-ctx + Erow ready

    // ---- ctx-half gates (h-half done in phase 0; both zero at t==0)
    if (t > 0 && h4 < 2) {
      const unsigned* xsrc = sm.xw + h4 * 72;
#pragma unroll
      for (int i = 0; i < 16; ++i) {
        uint4 xv = *reinterpret_cast<const uint4*>(xsrc + 4 * i);
        accg = dot2(wreg[4 * i + 0], xv.x, accg);
        accg = dot2(wreg[4 * i + 1], xv.y, accg);
        accg = dot2(wreg[4 * i + 2], xv.z, accg);
        accg = dot2(wreg[4 * i + 3], xv.w, accg);
      }
    }
    accg += __shfl_xor(accg, 1);
    accg += __shfl_xor(accg, 2);
    if (h4 == 0) sm.gout[r] = accg;
    __syncthreads();       // B3: gout ready

    // ---- LSTM pointwise + h publish (tagged)
    if (tid < 32) {
      float gi = sm.gout[tid]      + sm.Erow[tid];
      float gf = sm.gout[32 + tid] + sm.Erow[32 + tid];
      float gg = sm.gout[64 + tid] + sm.Erow[64 + tid];
      float go = sm.gout[96 + tid] + sm.Erow[96 + tid];
      float iv = sigmoidf_(gi), fv = sigmoidf_(gf), ov = sigmoidf_(go);
      float gv = tanh_fast(gg);
      c_reg = fv * c_reg + iv * gv;
      float hn = ov * tanh_fast(c_reg);
      hcb16[(size_t)(b * 128 + t) * 512 + ss * 32 + tid] = f2bf(hn);
      float ho = __shfl_xor(hn, 1);
      if (!(tid & 1)) {
        unsigned pk = packh2(hn, ho);
        int w = ss * 16 + (tid >> 1);
        sm.xw[xwi(128 + w)] = pk;
        gstore64(&Hx[(size_t)(t & 1) * 2048 + hxb + w],
                 ((ull)(unsigned)(t + 1) << 32) | pk);
      }
    }
    // ---- poll peers' h(t)
    if (tid < 128 && (tid >> 4) != ss) {
      const ull* hp = &Hx[(size_t)(t & 1) * 2048 + hxb + tid];
      ull w = gload64(hp);
      while ((unsigned)(w >> 32) != (unsigned)(t + 1)) {
        __builtin_amdgcn_s_sleep(1); w = gload64(hp);
      }
      sm.xw[xwi(128 + tid)] = (unsigned)w;
    }
    __syncthreads();       // B4: full h(t) in LDS

    // ---- scores: 64 keys, 8 lanes/key, shfl reduce
    {
      const int j = tid >> 3, qq = tid & 7;
      float acc2 = 0.f;
#pragma unroll
      for (int i = 0; i < 4; ++i) {
        uint4 kv = *reinterpret_cast<const uint4*>(&sm.k2p[j][qq * 16 + 4 * i]);
        uint4 hv = *reinterpret_cast<const uint4*>(&sm.xw[xwi(128 + qq * 16 + 4 * i)]);
        acc2 = dot2(kv.x, hv.x, acc2);
        acc2 = dot2(kv.y, hv.y, acc2);
        acc2 = dot2(kv.z, hv.z, acc2);
        acc2 = dot2(kv.w, hv.w, acc2);
      }
      acc2 += __shfl_xor(acc2, 1);
      acc2 += __shfl_xor(acc2, 2);
      acc2 += __shfl_xor(acc2, 4);
      if (qq == 0) sm.scores[j] = acc2;
    }
    __syncthreads();       // B5: scores ready
    if (tid < 64) {
      float s = sm.scores[tid] + sm.sbs[tid];
      float mx = s;
#pragma unroll
      for (int off = 1; off < 64; off <<= 1) mx = fmaxf(mx, __shfl_xor(mx, off));
      float p = __expf(s - mx);
      float ls = p;
#pragma unroll
      for (int off = 1; off < 64; off <<= 1) ls += __shfl_xor(ls, off);
      if (tid == 0) {
        ull tg = (ull)(unsigned)(t + 1) << 32;
        ull* PxS = Px + (size_t)(t & 1) * (16 * 8 * 130) + pxb + ss * 130;
        gstore64(&PxS[128], tg | __float_as_uint(mx));
        gstore64(&PxS[129], tg | __float_as_uint(ls));
      }
      float ph = __shfl_xor(p, 1);
      if (!(tid & 1)) sm.psp[tid >> 1] = packh2(p, ph);
    }
    __syncthreads();       // B6: psp ready
    // ---- PV: 1 thread per dim
    if (tid < 256) {
      float acc2 = 0.f;
#pragma unroll
      for (int jp = 0; jp < 32; ++jp) acc2 = dot2(sm.psp[jp], sm.vtp[tid][jp], acc2);
      float ao = __shfl_xor(acc2, 1);
      if (!(tid & 1)) {
        ull* PxS = Px + (size_t)(t & 1) * (16 * 8 * 130) + pxb + ss * 130;
        gstore64(&PxS[tid >> 1], ((ull)(unsigned)(t + 1) << 32) | packh2(acc2, ao));
      }
    }
    // no barrier: next iteration's tagged polls provide the ordering
  }
}

// ---------------------------------------------------------------------------
extern "C" void kernel_launch(void* const* d_in, const int* in_sizes, int n_in,
                              void* d_out, int out_size, void* d_ws, size_t ws_size,
                              hipStream_t stream)
{
  const int*   inputs   = (const int*)  d_in[0];
  const float* features = (const float*)d_in[1];
  const float* emb      = (const float*)d_in[2];
  const float* W_ih     = (const float*)d_in[3];
  const float* W_hh     = (const float*)d_in[4];
  const float* b_ih     = (const float*)d_in[5];
  const float* b_hh     = (const float*)d_in[6];
  const float* Wq       = (const float*)d_in[7];
  const float* bq       = (const float*)d_in[8];
  const float* Wk       = (const float*)d_in[9];
  const float* bk       = (const float*)d_in[10];
  const float* Wv       = (const float*)d_in[11];
  const float* bv       = (const float*)d_in[12];
  const float* Wo       = (const float*)d_in[13];
  const float* bo       = (const float*)d_in[14];
  float* out = (float*)d_out;

  char* ws = (char*)d_ws;
  size_t off = 0;
  auto alloc = [&](size_t bytes) -> char* {
    char* p = ws + off;
    off += (bytes + 255) & ~size_t(255);
    return p;
  };
  float*  keys  = (float*) alloc((size_t)8192 * 256 * 4);
  float*  vals  = (float*) alloc((size_t)8192 * 256 * 4);
  float*  K2    = (float*) alloc((size_t)8192 * 256 * 4);
  float*  E     = (float*) alloc((size_t)2048 * 1024 * 4);
  float*  WqT   = (float*) alloc((size_t)256 * 256 * 4);
  float*  sb    = (float*) alloc((size_t)8192 * 4);
  float*  bsum  = (float*) alloc((size_t)1024 * 4);
  ushort* hcb16 = (ushort*)alloc((size_t)2048 * 512 * 2);
  ull*    Hx    = (ull*)   alloc((size_t)2 * 16 * 128 * 8);
  ull*    Px    = (ull*)   alloc((size_t)2 * 16 * 8 * 130 * 8);

  // Wo in bf16 (32.8 MB) if workspace allows; numerically identical to the
  // per-tile f2bf the GEMM would otherwise do.
  const size_t woBytes = (size_t)32000 * 512 * 2;
  ushort* Wo16 = nullptr;
  if (off + woBytes + 256 <= ws_size) Wo16 = (ushort*)alloc(woBytes);

  hipMemsetAsync(Hx, 0, (size_t)2 * 16 * 128 * 8, stream);
  hipMemsetAsync(Px, 0, (size_t)2 * 16 * 8 * 130 * 8, stream);

  prep_kernel<<<260, 256, 0, stream>>>(Wq, WqT, b_ih, b_hh, bsum);

  gemm_kernel<true, false, false><<<dim3(64, 2), 256, 0, stream>>>(features, 512, nullptr, Wk, 512, bk, keys, 256, 512);
  gemm_kernel<true, false, false><<<dim3(64, 2), 256, 0, stream>>>(features, 512, nullptr, Wv, 512, bv, vals, 256, 512);
  gemm_kernel<true, false, false><<<dim3(64, 2), 256, 0, stream>>>(keys, 256, nullptr, WqT, 256, nullptr, K2, 256, 256);
  sb_kernel<<<2048, 256, 0, stream>>>(keys, bq, sb);
  gemm_kernel<true, false, false><<<dim3(16, 8), 256, 0, stream>>>(emb, 256, inputs, W_ih, 512, bsum, E, 1024, 256);

  if (Wo16) cvt_kernel<<<16000, 256, 0, stream>>>(Wo, Wo16, 32000 * 512 / 4);

  hipFuncSetAttribute(reinterpret_cast<const void*>(scan2_kernel),
                      hipFuncAttributeMaxDynamicSharedMemorySize, (int)sizeof(ScanSmem2));
  scan2_kernel<<<128, 512, sizeof(ScanSmem2), stream>>>(E, K2, sb, vals, W_ih, W_hh,
                                                        hcb16, Hx, Px);

  if (Wo16)
    gemm_kernel<false, true, true><<<dim3(16, 250), 256, 0, stream>>>(hcb16, 512, nullptr, Wo16, 512, bo, out, 32000, 512);
  else
    gemm_kernel<false, true, false><<<dim3(16, 250), 256, 0, stream>>>(hcb16, 512, nullptr, Wo, 512, bo, out, 32000, 512);
}

// Round 3
// 1400.672 us; speedup vs baseline: 1.2451x; 1.2451x over previous
//
#include <hip/hip_runtime.h>
#include <hip/hip_fp16.h>

#define DEVI __device__ __forceinline__

typedef __attribute__((ext_vector_type(4))) float f32x4;
typedef __attribute__((ext_vector_type(8))) short bf16x8;
typedef __attribute__((ext_vector_type(8))) _Float16 f16x8;
typedef __attribute__((ext_vector_type(2))) _Float16 f16x2;
typedef unsigned long long ull;

DEVI ushort f2bf(float x) {
  union { float f; unsigned u; } v; v.f = x;
  unsigned r = v.u + 0x7fffu + ((v.u >> 16) & 1u);
  return (ushort)(r >> 16);
}
DEVI float bf2f(ushort b) {
  union { unsigned u; float f; } v; v.u = ((unsigned)b) << 16; return v.f;
}
DEVI unsigned packh2(float a, float b) {
  return ((unsigned)__half_as_ushort(__float2half(b)) << 16) |
         (unsigned)__half_as_ushort(__float2half(a));
}
DEVI float dot2(unsigned a, unsigned b, float c) {
#if __has_builtin(__builtin_amdgcn_fdot2)
  return __builtin_amdgcn_fdot2(__builtin_bit_cast(f16x2, a),
                                __builtin_bit_cast(f16x2, b), c, false);
#else
  f16x2 ha = __builtin_bit_cast(f16x2, a), hb = __builtin_bit_cast(f16x2, b);
  return c + (float)ha[0] * (float)hb[0] + (float)ha[1] * (float)hb[1];
#endif
}
DEVI float sigmoidf_(float x) { return 1.f / (1.f + __expf(-x)); }
// NaN-free fast tanh: e=exp(2x); 1-2/(e+1). e=inf -> 1, e=0 -> -1.
DEVI float tanh_fast(float x) {
  float e = __expf(2.f * x);
  return 1.f - 2.f / (e + 1.f);
}

// relaxed agent-scope (L3 coherence point) 64-bit tagged-word accesses
DEVI void gstore64(ull* p, ull v) {
  __hip_atomic_store(p, v, __ATOMIC_RELAXED, __HIP_MEMORY_SCOPE_AGENT);
}
DEVI ull gload64(const ull* p) {
  return __hip_atomic_load(p, __ATOMIC_RELAXED, __HIP_MEMORY_SCOPE_AGENT);
}

// ---------------------------------------------------------------------------
// Generic 128x128-tile bf16 MFMA GEMM:  C[M,N] = A[M,K] @ Bw[N,K]^T + bias
// SPLIT=true: hi/lo split-bf16, 3 MFMA passes (~fp32 accuracy).
// ABF16/BBF16: operand already bf16 (ushort) in gmem.
// ---------------------------------------------------------------------------
template<bool SPLIT, bool ABF16, bool BBF16>
__global__ __launch_bounds__(256)
void gemm_kernel(const void* __restrict__ A_, int lda, const int* __restrict__ Aidx,
                 const void* __restrict__ Bw_, int ldb,
                 const float* __restrict__ bias, float* __restrict__ C,
                 int N, int K)
{
  constexpr int BK  = SPLIT ? 32 : 64;
  constexpr int LDT = BK + 8;
  constexpr int NV  = (128 * BK / 4) / 256;

  __shared__ ushort Ah[128 * LDT];
  __shared__ ushort Bh[128 * LDT];
  __shared__ ushort Al[SPLIT ? 128 * LDT : 4];
  __shared__ ushort Bl[SPLIT ? 128 * LDT : 4];

  const int tid  = threadIdx.x;
  const int bm   = blockIdx.x * 128, bn = blockIdx.y * 128;
  const int lane = tid & 63, wave = tid >> 6;
  const int wr   = wave >> 1, wc = wave & 1;
  const int fr   = lane & 15, quad = lane >> 4;

  f32x4 acc[4][4] = {};

  for (int kt = 0; kt < K; kt += BK) {
    __syncthreads();
#pragma unroll
    for (int i = 0; i < NV; ++i) {
      int v   = i * 256 + tid;
      int row = v / (BK / 4);
      int c4  = (v % (BK / 4)) * 4;
      int arow = Aidx ? Aidx[bm + row] : (bm + row);
      if (ABF16) {
        const ushort* A = (const ushort*)A_;
        ushort4 h = *reinterpret_cast<const ushort4*>(A + (size_t)arow * lda + kt + c4);
        *reinterpret_cast<ushort4*>(&Ah[row * LDT + c4]) = h;
      } else {
        const float* A = (const float*)A_;
        const float4 x = *reinterpret_cast<const float4*>(A + (size_t)arow * lda + kt + c4);
        ushort4 h; h.x = f2bf(x.x); h.y = f2bf(x.y); h.z = f2bf(x.z); h.w = f2bf(x.w);
        *reinterpret_cast<ushort4*>(&Ah[row * LDT + c4]) = h;
        if (SPLIT) {
          ushort4 l;
          l.x = f2bf(x.x - bf2f(h.x)); l.y = f2bf(x.y - bf2f(h.y));
          l.z = f2bf(x.z - bf2f(h.z)); l.w = f2bf(x.w - bf2f(h.w));
          *reinterpret_cast<ushort4*>(&Al[row * LDT + c4]) = l;
        }
      }
    }
#pragma unroll
    for (int i = 0; i < NV; ++i) {
      int v   = i * 256 + tid;
      int row = v / (BK / 4);
      int c4  = (v % (BK / 4)) * 4;
      if (BBF16) {
        const ushort* B16 = (const ushort*)Bw_;
        ushort4 h = *reinterpret_cast<const ushort4*>(B16 + (size_t)(bn + row) * ldb + kt + c4);
        *reinterpret_cast<ushort4*>(&Bh[row * LDT + c4]) = h;
      } else {
        const float* Bw = (const float*)Bw_;
        const float4 x = *reinterpret_cast<const float4*>(Bw + (size_t)(bn + row) * ldb + kt + c4);
        ushort4 h; h.x = f2bf(x.x); h.y = f2bf(x.y); h.z = f2bf(x.z); h.w = f2bf(x.w);
        *reinterpret_cast<ushort4*>(&Bh[row * LDT + c4]) = h;
        if (SPLIT) {
          ushort4 l;
          l.x = f2bf(x.x - bf2f(h.x)); l.y = f2bf(x.y - bf2f(h.y));
          l.z = f2bf(x.z - bf2f(h.z)); l.w = f2bf(x.w - bf2f(h.w));
          *reinterpret_cast<ushort4*>(&Bl[row * LDT + c4]) = l;
        }
      }
    }
    __syncthreads();
#pragma unroll
    for (int ks = 0; ks < BK; ks += 32) {
      bf16x8 ah[4], bh[4];
#pragma unroll
      for (int i = 0; i < 4; ++i) {
        ah[i] = *reinterpret_cast<const bf16x8*>(&Ah[(wr * 64 + i * 16 + fr) * LDT + ks + quad * 8]);
        bh[i] = *reinterpret_cast<const bf16x8*>(&Bh[(wc * 64 + i * 16 + fr) * LDT + ks + quad * 8]);
      }
      if (SPLIT) {
        bf16x8 al[4], bl[4];
#pragma unroll
        for (int i = 0; i < 4; ++i) {
          al[i] = *reinterpret_cast<const bf16x8*>(&Al[(wr * 64 + i * 16 + fr) * LDT + ks + quad * 8]);
          bl[i] = *reinterpret_cast<const bf16x8*>(&Bl[(wc * 64 + i * 16 + fr) * LDT + ks + quad * 8]);
        }
#pragma unroll
        for (int i = 0; i < 4; ++i)
#pragma unroll
          for (int j = 0; j < 4; ++j) {
            acc[i][j] = __builtin_amdgcn_mfma_f32_16x16x32_bf16(ah[i], bh[j], acc[i][j], 0, 0, 0);
            acc[i][j] = __builtin_amdgcn_mfma_f32_16x16x32_bf16(ah[i], bl[j], acc[i][j], 0, 0, 0);
            acc[i][j] = __builtin_amdgcn_mfma_f32_16x16x32_bf16(al[i], bh[j], acc[i][j], 0, 0, 0);
          }
      } else {
#pragma unroll
        for (int i = 0; i < 4; ++i)
#pragma unroll
          for (int j = 0; j < 4; ++j)
            acc[i][j] = __builtin_amdgcn_mfma_f32_16x16x32_bf16(ah[i], bh[j], acc[i][j], 0, 0, 0);
      }
    }
  }
#pragma unroll
  for (int i = 0; i < 4; ++i)
#pragma unroll
    for (int j = 0; j < 4; ++j)
#pragma unroll
      for (int r = 0; r < 4; ++r) {
        int m = bm + wr * 64 + i * 16 + quad * 4 + r;
        int n = bn + wc * 64 + j * 16 + fr;
        float vv = acc[i][j][r];
        if (bias) vv += bias[n];
        C[(size_t)m * N + n] = vv;
      }
}

// ---------------------------------------------------------------------------
__global__ void prep_kernel(const float* __restrict__ Wq, float* __restrict__ WqT,
                            const float* __restrict__ b_ih, const float* __restrict__ b_hh,
                            float* __restrict__ bsum)
{
  int idx = blockIdx.x * 256 + threadIdx.x;
  if (idx < 65536) {
    int e = idx >> 8, d = idx & 255;
    WqT[idx] = Wq[d * 256 + e];
  } else if (idx < 66560) {
    int n = idx - 65536;
    bsum[n] = b_ih[n] + b_hh[n];
  }
}

// sb[r] = keys[r,:] . bq
__global__ void sb_kernel(const float* __restrict__ keys, const float* __restrict__ bq,
                          float* __restrict__ sb)
{
  int row  = blockIdx.x * 4 + (threadIdx.x >> 6);
  int lane = threadIdx.x & 63;
  const float* kr = keys + (size_t)row * 256;
  float acc = kr[lane] * bq[lane] + kr[64 + lane] * bq[64 + lane]
            + kr[128 + lane] * bq[128 + lane] + kr[192 + lane] * bq[192 + lane];
#pragma unroll
  for (int off = 1; off < 64; off <<= 1) acc += __shfl_xor(acc, off);
  if (lane == 0) sb[row] = acc;
}

// f32 -> bf16 convert
__global__ void cvt_kernel(const float* __restrict__ src, ushort* __restrict__ dst, int n4)
{
  int i = blockIdx.x * 256 + threadIdx.x;
  if (i < n4) {
    float4 x = reinterpret_cast<const float4*>(src)[i];
    ushort4 h; h.x = f2bf(x.x); h.y = f2bf(x.y); h.z = f2bf(x.z); h.w = f2bf(x.w);
    reinterpret_cast<ushort4*>(dst)[i] = h;
  }
}

// ---------------------------------------------------------------------------
// Sequential scan, batch-decoupled: 16 independent groups of 8 blocks.
// Tagged 64-bit payloads (hi32 = t+1), parity double-buffered.
// Combine polls are DISTRIBUTED (tid<16 handle m/l -> LDS; each thread polls
// only its 2 ctx words) — round-2's all-threads-poll-all regressed 280us from
// coherence-point contention. Scores use stride-131 scalar LDS reads (2-way,
// free) — round-2's stride-132 uint4 was an 8-way bank conflict (17.8M).
// Wh@h gate half overlaps the first RT window; fast tanh in the serial lane.
// ---------------------------------------------------------------------------
struct ScanSmem2 {
  unsigned k2p[64][131];   // K2 slice, f16 pairs (stride 131: 2-way banks, free)
  unsigned vtp[256][35];   // V slice transposed [e][jp]
  unsigned xw[288];        // x = [ctx|h] f16 pairs, 4 chunks x 72
  unsigned psp[32];        // softmax p, f16 pairs
  float Erow[128];
  float gout[128];
  float ml[8][2];          // per-slice (m, l)
  float cpart[4][128][2];  // ctx combine partials
  float sc[8][64];         // score partials
  float sbs[64];
};

DEVI int xwi(int w) { return (w >> 6) * 72 + (w & 63); }

__global__ __launch_bounds__(512, 1)
void scan2_kernel(const float* __restrict__ E, const float* __restrict__ K2g,
                  const float* __restrict__ sbg, const float* __restrict__ valg,
                  const float* __restrict__ W_ih, const float* __restrict__ W_hh,
                  ushort* __restrict__ hcb16,
                  ull* __restrict__ Hx,    // [2][16][128]
                  ull* __restrict__ Px)    // [2][16][8][130]
{
  extern __shared__ char smraw[];
  ScanSmem2& sm = *reinterpret_cast<ScanSmem2*>(smraw);
  const int g = blockIdx.x, tid = threadIdx.x;
  const int b = g >> 3, ss = g & 7;

  // ---- persistent LDS init
  for (int idx = tid; idx < 64 * 128; idx += 512) {
    int j = idx >> 7, i = idx & 127;
    const float* src = K2g + (size_t)(b * 512 + ss * 64 + j) * 256 + 2 * i;
    sm.k2p[j][i] = packh2(src[0], src[1]);
  }
  for (int idx = tid; idx < 256 * 32; idx += 512) {
    int e = idx >> 5, jp = idx & 31;
    float v0 = valg[(size_t)(b * 512 + ss * 64 + 2 * jp) * 256 + e];
    float v1 = valg[(size_t)(b * 512 + ss * 64 + 2 * jp + 1) * 256 + e];
    sm.vtp[e][jp] = packh2(v0, v1);
  }
  if (tid < 64) sm.sbs[tid] = sbg[b * 512 + ss * 64 + tid];
  for (int i = tid; i < 288; i += 512) sm.xw[i] = 0;   // ctx0 = h0 = 0

  // ---- gate-weight slice -> registers (f16 pairs), 4 threads per gate row
  const int r  = tid >> 2, h4 = tid & 3;
  const int grow = (r >> 5) * 256 + ss * 32 + (r & 31);  // PyTorch i,f,g,o order
  const float* wsrc = (h4 < 2)
      ? (W_ih + (size_t)grow * 512 + 256 + h4 * 128)     // x[0:256] = ctx
      : (W_hh + (size_t)grow * 256 + (h4 - 2) * 128);    // x[256:512] = h
  unsigned wreg[64];
#pragma unroll
  for (int i = 0; i < 32; ++i) {
    float4 w4 = reinterpret_cast<const float4*>(wsrc)[i];
    wreg[2 * i]     = packh2(w4.x, w4.y);
    wreg[2 * i + 1] = packh2(w4.z, w4.w);
  }

  float c_reg = 0.f;          // cell state, tid<32 only
  __syncthreads();

  const size_t hxb = (size_t)b * 128;
  const size_t pxb = (size_t)b * (8 * 130);

  for (int t = 0; t <= 128; ++t) {
    // E prefetch for this step
    float epf = 0.f;
    if (t < 128 && tid < 128)
      epf = E[(size_t)(b * 128 + t) * 1024 + (tid >> 5) * 256 + ss * 32 + (tid & 31)];

    float accg = 0.f;
    if (t > 0) {
      const unsigned tag = (unsigned)t;
      const ull* PxP = Px + (size_t)((t - 1) & 1) * (16 * 8 * 130) + pxb;
      const int e2 = tid & 127, q = tid >> 7;
      const ull* p1 = &PxP[(2 * q) * 130 + e2];
      const ull* p2 = &PxP[(2 * q + 1) * 130 + e2];
      // issue poll loads first: 2 ctx words/thread + (tid<16) 1 m/l word
      ull w1 = gload64(p1), w2 = gload64(p2);
      const ull* pm = &PxP[(tid >> 1) * 130 + 128 + (tid & 1)];
      ull wm = (tid < 16) ? gload64(pm) : 0;

      // ---- Wh @ h(t-1) half of the gate matvec, under the RT window
      if (h4 >= 2) {
        const unsigned* xsrc = sm.xw + h4 * 72;
#pragma unroll
        for (int i = 0; i < 16; ++i) {
          uint4 xv = *reinterpret_cast<const uint4*>(xsrc + 4 * i);
          accg = dot2(wreg[4 * i + 0], xv.x, accg);
          accg = dot2(wreg[4 * i + 1], xv.y, accg);
          accg = dot2(wreg[4 * i + 2], xv.z, accg);
          accg = dot2(wreg[4 * i + 3], xv.w, accg);
        }
      }

      if (tid < 16) {
        while ((unsigned)(wm >> 32) != tag) { __builtin_amdgcn_s_sleep(1); wm = gload64(pm); }
        sm.ml[tid >> 1][tid & 1] = __uint_as_float((unsigned)wm);
      }
      while ((unsigned)(w1 >> 32) != tag) { __builtin_amdgcn_s_sleep(1); w1 = gload64(p1); }
      while ((unsigned)(w2 >> 32) != tag) { __builtin_amdgcn_s_sleep(1); w2 = gload64(p2); }
      __syncthreads();   // B1: sm.ml ready
      float M = sm.ml[0][0];
#pragma unroll
      for (int s3 = 1; s3 < 8; ++s3) M = fmaxf(M, sm.ml[s3][0]);
      float L = 0.f;
#pragma unroll
      for (int s3 = 0; s3 < 8; ++s3) L += sm.ml[s3][1] * __expf(sm.ml[s3][0] - M);
      float rcpL = 1.f / L;
      float wf0 = __expf(sm.ml[2 * q][0] - M);
      float wf1 = __expf(sm.ml[2 * q + 1][0] - M);
      f16x2 x1 = __builtin_bit_cast(f16x2, (unsigned)w1);
      f16x2 x2 = __builtin_bit_cast(f16x2, (unsigned)w2);
      sm.cpart[q][e2][0] = wf0 * (float)x1[0] + wf1 * (float)x2[0];
      sm.cpart[q][e2][1] = wf0 * (float)x1[1] + wf1 * (float)x2[1];
      __syncthreads();   // B2: cpart ready
      if (tid < 128) {
        float c0 = (sm.cpart[0][tid][0] + sm.cpart[1][tid][0]
                  + sm.cpart[2][tid][0] + sm.cpart[3][tid][0]) * rcpL;
        float c1 = (sm.cpart[0][tid][1] + sm.cpart[1][tid][1]
                  + sm.cpart[2][tid][1] + sm.cpart[3][tid][1]) * rcpL;
        sm.xw[xwi(tid)] = packh2(c0, c1);
        ushort* dst = hcb16 + (size_t)(b * 128 + (t - 1)) * 512 + 256 + 2 * tid;
        dst[0] = f2bf(c0); dst[1] = f2bf(c1);
      }
    }
    if (t == 128) break;
    if (tid < 128) sm.Erow[tid] = epf;
    __syncthreads();     // B3: xw-ctx + Erow ready

    // ---- ctx-half gates (h-half done under the RT; both zero at t==0)
    if (t > 0 && h4 < 2) {
      const unsigned* xsrc = sm.xw + h4 * 72;
#pragma unroll
      for (int i = 0; i < 16; ++i) {
        uint4 xv = *reinterpret_cast<const uint4*>(xsrc + 4 * i);
        accg = dot2(wreg[4 * i + 0], xv.x, accg);
        accg = dot2(wreg[4 * i + 1], xv.y, accg);
        accg = dot2(wreg[4 * i + 2], xv.z, accg);
        accg = dot2(wreg[4 * i + 3], xv.w, accg);
      }
    }
    accg += __shfl_xor(accg, 1);
    accg += __shfl_xor(accg, 2);
    if (h4 == 0) sm.gout[r] = accg;
    __syncthreads();     // B4: gout ready

    // ---- LSTM pointwise + h publish (tagged)
    if (tid < 32) {
      float gi = sm.gout[tid]      + sm.Erow[tid];
      float gf = sm.gout[32 + tid] + sm.Erow[32 + tid];
      float gg = sm.gout[64 + tid] + sm.Erow[64 + tid];
      float go = sm.gout[96 + tid] + sm.Erow[96 + tid];
      float iv = sigmoidf_(gi), fv = sigmoidf_(gf), ov = sigmoidf_(go);
      float gv = tanh_fast(gg);
      c_reg = fv * c_reg + iv * gv;
      float hn = ov * tanh_fast(c_reg);
      hcb16[(size_t)(b * 128 + t) * 512 + ss * 32 + tid] = f2bf(hn);
      float ho = __shfl_xor(hn, 1);
      if (!(tid & 1)) {
        unsigned pk = packh2(hn, ho);
        int w = ss * 16 + (tid >> 1);
        sm.xw[xwi(128 + w)] = pk;
        gstore64(&Hx[(size_t)(t & 1) * 2048 + hxb + w],
                 ((ull)(unsigned)(t + 1) << 32) | pk);
      }
    }
    // ---- poll peers' h(t)
    if (tid < 128 && (tid >> 4) != ss) {
      const ull* hp = &Hx[(size_t)(t & 1) * 2048 + hxb + tid];
      ull w = gload64(hp);
      while ((unsigned)(w >> 32) != (unsigned)(t + 1)) {
        __builtin_amdgcn_s_sleep(1); w = gload64(hp);
      }
      sm.xw[xwi(128 + tid)] = (unsigned)w;
    }
    __syncthreads();     // B5: full h(t) in LDS

    // ---- scores: 64 keys x 256; lane = key row (stride-131 2-way, free),
    //      h words broadcast within wave
    {
      const int j = tid & 63, qq = tid >> 6;
      float acc2 = 0.f;
#pragma unroll
      for (int i = 0; i < 16; ++i)
        acc2 = dot2(sm.k2p[j][qq * 16 + i], sm.xw[xwi(128 + qq * 16 + i)], acc2);
      sm.sc[qq][j] = acc2;
    }
    __syncthreads();     // B6: score partials ready
    if (tid < 64) {
      float s = sm.sc[0][tid] + sm.sc[1][tid] + sm.sc[2][tid] + sm.sc[3][tid]
              + sm.sc[4][tid] + sm.sc[5][tid] + sm.sc[6][tid] + sm.sc[7][tid]
              + sm.sbs[tid];
      float mx = s;
#pragma unroll
      for (int off = 1; off < 64; off <<= 1) mx = fmaxf(mx, __shfl_xor(mx, off));
      float p = __expf(s - mx);
      float ls = p;
#pragma unroll
      for (int off = 1; off < 64; off <<= 1) ls += __shfl_xor(ls, off);
      if (tid == 0) {
        ull tg = (ull)(unsigned)(t + 1) << 32;
        ull* PxS = Px + (size_t)(t & 1) * (16 * 8 * 130) + pxb + ss * 130;
        gstore64(&PxS[128], tg | __float_as_uint(mx));
        gstore64(&PxS[129], tg | __float_as_uint(ls));
      }
      float ph = __shfl_xor(p, 1);
      if (!(tid & 1)) sm.psp[tid >> 1] = packh2(p, ph);
    }
    __syncthreads();     // B7: psp ready
    // ---- PV: 1 thread per dim (psp broadcast, vtp stride-35 2-way free)
    if (tid < 256) {
      float acc2 = 0.f;
#pragma unroll
      for (int jp = 0; jp < 32; ++jp) acc2 = dot2(sm.psp[jp], sm.vtp[tid][jp], acc2);
      float ao = __shfl_xor(acc2, 1);
      if (!(tid & 1)) {
        ull* PxS = Px + (size_t)(t & 1) * (16 * 8 * 130) + pxb + ss * 130;
        gstore64(&PxS[tid >> 1], ((ull)(unsigned)(t + 1) << 32) | packh2(acc2, ao));
      }
    }
    // no barrier: next iteration's tagged polls provide the ordering
  }
}

// ---------------------------------------------------------------------------
extern "C" void kernel_launch(void* const* d_in, const int* in_sizes, int n_in,
                              void* d_out, int out_size, void* d_ws, size_t ws_size,
                              hipStream_t stream)
{
  const int*   inputs   = (const int*)  d_in[0];
  const float* features = (const float*)d_in[1];
  const float* emb      = (const float*)d_in[2];
  const float* W_ih     = (const float*)d_in[3];
  const float* W_hh     = (const float*)d_in[4];
  const float* b_ih     = (const float*)d_in[5];
  const float* b_hh     = (const float*)d_in[6];
  const float* Wq       = (const float*)d_in[7];
  const float* bq       = (const float*)d_in[8];
  const float* Wk       = (const float*)d_in[9];
  const float* bk       = (const float*)d_in[10];
  const float* Wv       = (const float*)d_in[11];
  const float* bv       = (const float*)d_in[12];
  const float* Wo       = (const float*)d_in[13];
  const float* bo       = (const float*)d_in[14];
  float* out = (float*)d_out;

  char* ws = (char*)d_ws;
  size_t off = 0;
  auto alloc = [&](size_t bytes) -> char* {
    char* p = ws + off;
    off += (bytes + 255) & ~size_t(255);
    return p;
  };
  float*  keys  = (float*) alloc((size_t)8192 * 256 * 4);
  float*  vals  = (float*) alloc((size_t)8192 * 256 * 4);
  float*  K2    = (float*) alloc((size_t)8192 * 256 * 4);
  float*  E     = (float*) alloc((size_t)2048 * 1024 * 4);
  float*  WqT   = (float*) alloc((size_t)256 * 256 * 4);
  float*  sb    = (float*) alloc((size_t)8192 * 4);
  float*  bsum  = (float*) alloc((size_t)1024 * 4);
  ushort* hcb16 = (ushort*)alloc((size_t)2048 * 512 * 2);
  ull*    Hx    = (ull*)   alloc((size_t)2 * 16 * 128 * 8);
  ull*    Px    = (ull*)   alloc((size_t)2 * 16 * 8 * 130 * 8);

  // Wo in bf16 (32.8 MB) if workspace allows; numerically identical to the
  // per-tile f2bf the GEMM would otherwise do.
  const size_t woBytes = (size_t)32000 * 512 * 2;
  ushort* Wo16 = nullptr;
  if (off + woBytes + 256 <= ws_size) Wo16 = (ushort*)alloc(woBytes);

  hipMemsetAsync(Hx, 0, (size_t)2 * 16 * 128 * 8, stream);
  hipMemsetAsync(Px, 0, (size_t)2 * 16 * 8 * 130 * 8, stream);

  prep_kernel<<<260, 256, 0, stream>>>(Wq, WqT, b_ih, b_hh, bsum);

  gemm_kernel<true, false, false><<<dim3(64, 2), 256, 0, stream>>>(features, 512, nullptr, Wk, 512, bk, keys, 256, 512);
  gemm_kernel<true, false, false><<<dim3(64, 2), 256, 0, stream>>>(features, 512, nullptr, Wv, 512, bv, vals, 256, 512);
  gemm_kernel<true, false, false><<<dim3(64, 2), 256, 0, stream>>>(keys, 256, nullptr, WqT, 256, nullptr, K2, 256, 256);
  sb_kernel<<<2048, 256, 0, stream>>>(keys, bq, sb);
  gemm_kernel<true, false, false><<<dim3(16, 8), 256, 0, stream>>>(emb, 256, inputs, W_ih, 512, bsum, E, 1024, 256);

  if (Wo16) cvt_kernel<<<16000, 256, 0, stream>>>(Wo, Wo16, 32000 * 512 / 4);

  hipFuncSetAttribute(reinterpret_cast<const void*>(scan2_kernel),
                      hipFuncAttributeMaxDynamicSharedMemorySize, (int)sizeof(ScanSmem2));
  scan2_kernel<<<128, 512, sizeof(ScanSmem2), stream>>>(E, K2, sb, vals, W_ih, W_hh,
                                                        hcb16, Hx, Px);

  if (Wo16)
    gemm_kernel<false, true, true><<<dim3(16, 250), 256, 0, stream>>>(hcb16, 512, nullptr, Wo16, 512, bo, out, 32000, 512);
  else
    gemm_kernel<false, true, false><<<dim3(16, 250), 256, 0, stream>>>(hcb16, 512, nullptr, Wo, 512, bo, out, 32000, 512);
}